// Round 18
// baseline (364.743 us; speedup 1.0000x reference)
//
#include <hip/hip_runtime.h>

// Problem constants: B=128, L=512, D=256, H=128, 4H=512, both dirs fused NG=1024
#define NB 128
#define NL 512
#define ND 256
#define NG 1024

typedef __attribute__((ext_vector_type(8))) short bfv8;
typedef __attribute__((ext_vector_type(4))) float f32x4;

typedef __attribute__((address_space(1))) const unsigned int glo_u32;
typedef __attribute__((address_space(3))) unsigned int lds_u32;

#define LOG2E 1.4426950408889634f
#define NSCALE (-1.4426950408889634f)   // i,f,o gate rows: t = -x*log2e
#define GSCALE (2.8853900817779268f)    // g gate rows: t = 2x*log2e

__device__ __forceinline__ unsigned short f2bf(float f) {
    unsigned u = __float_as_uint(f);
    u += 0x7fffu + ((u >> 16) & 1u);   // round-to-nearest-even
    return (unsigned short)(u >> 16);
}
__device__ __forceinline__ float bf2f(unsigned short u) {
    return __uint_as_float(((unsigned)u) << 16);
}

// ---------------------------------------------------------------------------
// 1) convert+transpose: xbt[l*128+b][d] = bf16(x[b][l][d])
// ---------------------------------------------------------------------------
__global__ __launch_bounds__(256) void convert_kernel(const float* __restrict__ x,
                                                      unsigned short* __restrict__ xbt) {
    size_t t = (size_t)blockIdx.x * 256 + threadIdx.x;
    size_t e = t * 4;                       // flat idx into x, 4 floats per thread
    int d = (int)(e & 255u);
    int l = (int)((e >> 8) & 511u);
    int b = (int)(e >> 17);
    float4 v = *(const float4*)(x + e);
    ushort4 o;
    o.x = f2bf(v.x); o.y = f2bf(v.y); o.z = f2bf(v.z); o.w = f2bf(v.w);
    *(ushort4*)(xbt + ((size_t)(l * NB + b)) * ND + d) = o;
}

// ---------------------------------------------------------------------------
// 2) fold: Weff[g][k] = scale(g) * sum_d Wih[row(g)][d] * W_proj[d][k]
//    Rows reordered g = dir*512 + hid*4 + gate; gate order i,f,g,o.
//    EXP2-DOMAIN scaling folded in: i,f,o rows x(-log2e), g rows x(+2 log2e)
// ---------------------------------------------------------------------------
__global__ __launch_bounds__(256) void fold_kernel(const float* __restrict__ Wproj,
                                                   const float* __restrict__ bproj,
                                                   const float* __restrict__ Wih_f,
                                                   const float* __restrict__ b_f,
                                                   const float* __restrict__ Wih_b,
                                                   const float* __restrict__ b_b,
                                                   unsigned short* __restrict__ weff,
                                                   float* __restrict__ beff) {
    int g = blockIdx.x;            // 0..1023 (reordered output row)
    int k = threadIdx.x;           // 0..255
    int dirg = g >> 9;
    int rem  = g & 511;
    int hidg = rem >> 2;
    int gate = rem & 3;
    int srcrow = gate * 128 + hidg;
    float scale = (gate == 2) ? GSCALE : NSCALE;
    const float* Wih = dirg ? (Wih_b + (size_t)srcrow * ND) : (Wih_f + (size_t)srcrow * ND);
    float acc = 0.f;
    for (int d = 0; d < ND; ++d)
        acc += Wih[d] * Wproj[(size_t)d * ND + k];
    weff[(size_t)g * ND + k] = f2bf(acc * scale);
    if (k == 0) {
        float ab = dirg ? b_b[srcrow] : b_f[srcrow];
        for (int d = 0; d < ND; ++d) ab += Wih[d] * bproj[d];
        beff[g] = ab * scale;
    }
}

// ---------------------------------------------------------------------------
// 3) pre-GEMM: C[r][g] = bf16( A[r][:] . Bw[g][:] + bias[g] )
//    128x128 tile, BK=32, 4 waves (2x2), 16x16x32 bf16 MFMA.
//    global_load_lds width-16 staging; LDS dest linear, XOR swizzle applied
//    on the SOURCE chunk ((lane&3)^(row&3)); read side uses same involution.
// ---------------------------------------------------------------------------
__global__ __launch_bounds__(256, 2) void gemm_pre(const unsigned short* __restrict__ A,
                                                   const unsigned short* __restrict__ Bw,
                                                   const float* __restrict__ bias,
                                                   unsigned short* __restrict__ C) {
    __shared__ unsigned short As[128 * 32];
    __shared__ unsigned short Bs[128 * 32];
    const int tid = threadIdx.x;
    const int lane = tid & 63;
    const int wid = tid >> 6;
    const int m0 = blockIdx.y * 128;
    const int n0 = blockIdx.x * 128;
    const int wm = (wid >> 1) * 64;
    const int wn = (wid & 1) * 64;

    f32x4 acc[4][4] = {};

    const int srow = tid >> 2;                 // = 16*wid + (lane>>2), 0..63
    const int csrc = (lane & 3) ^ (srow & 3);  // pre-swizzled source chunk
    unsigned short* a_l0 = As + wid * 512;
    unsigned short* a_l1 = As + 2048 + wid * 512;
    unsigned short* b_l0 = Bs + wid * 512;
    unsigned short* b_l1 = Bs + 2048 + wid * 512;

    for (int it = 0; it < 8; ++it) {
        __syncthreads();                       // prior compute done; LDS reusable
        const int kb = it * 32;
        const unsigned short* ga0 = A  + (size_t)(m0 + srow) * ND + kb + csrc * 8;
        const unsigned short* ga1 = A  + (size_t)(m0 + srow + 64) * ND + kb + csrc * 8;
        const unsigned short* gb0 = Bw + (size_t)(n0 + srow) * ND + kb + csrc * 8;
        const unsigned short* gb1 = Bw + (size_t)(n0 + srow + 64) * ND + kb + csrc * 8;
        __builtin_amdgcn_global_load_lds((glo_u32*)ga0, (lds_u32*)a_l0, 16, 0, 0);
        __builtin_amdgcn_global_load_lds((glo_u32*)ga1, (lds_u32*)a_l1, 16, 0, 0);
        __builtin_amdgcn_global_load_lds((glo_u32*)gb0, (lds_u32*)b_l0, 16, 0, 0);
        __builtin_amdgcn_global_load_lds((glo_u32*)gb1, (lds_u32*)b_l1, 16, 0, 0);
        __syncthreads();                       // vmcnt(0) drained -> tile ready

        const int r = lane & 15;
        const int kq = lane >> 4;
        bfv8 af[4], bfr[4];
        #pragma unroll
        for (int m = 0; m < 4; ++m) {
            int rw = wm + m * 16 + r;
            af[m] = *(const bfv8*)(As + rw * 32 + ((((kq << 4) ^ ((rw & 3) << 4))) >> 1));
        }
        #pragma unroll
        for (int n = 0; n < 4; ++n) {
            int rw = wn + n * 16 + r;
            bfr[n] = *(const bfv8*)(Bs + rw * 32 + ((((kq << 4) ^ ((rw & 3) << 4))) >> 1));
        }
        #pragma unroll
        for (int m = 0; m < 4; ++m)
            #pragma unroll
            for (int n = 0; n < 4; ++n)
                acc[m][n] = __builtin_amdgcn_mfma_f32_16x16x32_bf16(af[m], bfr[n], acc[m][n], 0, 0, 0);
    }

    const int r = lane & 15;
    const int rq = lane >> 4;
    #pragma unroll
    for (int n = 0; n < 4; ++n) {
        int col = n0 + wn + n * 16 + r;
        float bv = bias[col];
        #pragma unroll
        for (int m = 0; m < 4; ++m) {
            #pragma unroll
            for (int v = 0; v < 4; ++v) {
                int rowg = m0 + wm + m * 16 + rq * 4 + v;
                C[(size_t)rowg * NG + col] = f2bf(acc[m][n][v] + bv);
            }
        }
    }
}

// ---------------------------------------------------------------------------
// 4) LSTM scan: r14 structure (measured local floor: 259/267/263 over r14-17).
//    THIS ROUND'S single change: relax the pre-barrier scheduling pin.
//    Old: sched_barrier(0); lgkmcnt(0); s_barrier; sched_barrier(0)
//    New: lgkmcnt(0) with "memory" clobber (keeps h-store -> wait -> barrier
//    protocol); only the POST-barrier sched_barrier(0) retained (rule #18).
//    Mechanism: scheduler may float independent tail ops (pP rotation,
//    next-step SALU, late ACT of other gates) into the wait shadow.
// ---------------------------------------------------------------------------
struct ScanSM {
    unsigned short h[2][136];      // [buf][hid] bf16
    char pin[81700];               // total 82244 B > 81920 -> 1 block/CU
};

#define MFMA16(a, b, c) __builtin_amdgcn_mfma_f32_16x16x32_bf16((a), (b), (c), 0, 0, 0)

#define STEP(S, CURB, NXTB)                                                    \
  {                                                                            \
    int rr = (S) + 2; if (rr > 511) rr = 511;          /* uniform SALU */      \
    int tts = dirs ? (511 - rr) : rr;                                          \
    const unsigned short* rowp = pdb + (size_t)tts * (NB * NG);                \
    uint2 nx = *(const uint2*)(rowp + hid4);           /* saddr + v_off */     \
    bfv8 ha0 = *(const bfv8*)&sm.h[CURB][q * 8];                               \
    bfv8 ha1 = *(const bfv8*)&sm.h[CURB][32 + q * 8];                          \
    bfv8 ha2 = *(const bfv8*)&sm.h[CURB][64 + q * 8];                          \
    bfv8 ha3 = *(const bfv8*)&sm.h[CURB][96 + q * 8];                          \
    f32x4 z = {0.f, 0.f, 0.f, 0.f};                                            \
    f32x4 acci = MFMA16(ha0, bfr[0][0], z);                                    \
    f32x4 accf = MFMA16(ha0, bfr[1][0], z);                                    \
    f32x4 accg = MFMA16(ha0, bfr[2][0], z);                                    \
    f32x4 acco = MFMA16(ha0, bfr[3][0], z);                                    \
    acci = MFMA16(ha1, bfr[0][1], acci); accf = MFMA16(ha1, bfr[1][1], accf);  \
    accg = MFMA16(ha1, bfr[2][1], accg); acco = MFMA16(ha1, bfr[3][1], acco);  \
    acci = MFMA16(ha2, bfr[0][2], acci); accf = MFMA16(ha2, bfr[1][2], accf);  \
    accg = MFMA16(ha2, bfr[2][2], accg); acco = MFMA16(ha2, bfr[3][2], acco);  \
    acci = MFMA16(ha3, bfr[0][3], acci); accf = MFMA16(ha3, bfr[1][3], accf);  \
    accg = MFMA16(ha3, bfr[2][3], accg); acco = MFMA16(ha3, bfr[3][3], acco);  \
    int tt = dirs ? (511 - (S)) : (S);                                         \
    {                                                                          \
        float pi = __uint_as_float(pP0.x << 16);                               \
        float pf = __uint_as_float(pP0.x & 0xffff0000u);                       \
        float pg = __uint_as_float(pP0.y << 16);                               \
        float po = __uint_as_float(pP0.y & 0xffff0000u);                       \
        /* scaled domain: t_ifo = -x*log2e, t_g = 2x*log2e (folded) */         \
        float ia = __builtin_amdgcn_rcpf(1.f + __builtin_amdgcn_exp2f(acci[0] + pi)); \
        float fa = __builtin_amdgcn_rcpf(1.f + __builtin_amdgcn_exp2f(accf[0] + pf)); \
        float rg = __builtin_amdgcn_rcpf(1.f + __builtin_amdgcn_exp2f(accg[0] + pg)); \
        float oa = __builtin_amdgcn_rcpf(1.f + __builtin_amdgcn_exp2f(acco[0] + po)); \
        float ga = fmaf(-2.f, rg, 1.f);                                        \
        c0 = fmaf(fa, c0, ia * ga);                                            \
        float rc = __builtin_amdgcn_rcpf(1.f + __builtin_amdgcn_exp2f(c0 * GSCALE)); \
        float th = fmaf(-2.f, rc, 1.f);                                        \
        unsigned short us = f2bf(oa * th);                                     \
        if (q == 0) {                                                          \
            sm.h[NXTB][hid] = us;                                              \
            hsrow[(size_t)tt * 256 + hid] = us;                                \
        }                                                                      \
    }                                                                          \
    pP0 = pP1; pP1 = nx;                                                       \
    asm volatile("s_waitcnt lgkmcnt(0)" ::: "memory");                         \
    __builtin_amdgcn_s_barrier();                                              \
    __builtin_amdgcn_sched_barrier(0);                                         \
  }

__global__ void __launch_bounds__(512)
scan_kernel(const unsigned short* __restrict__ pre,
            const float* __restrict__ Whh_f,
            const float* __restrict__ Whh_b,
            unsigned short* __restrict__ hs) {
    const int b    = blockIdx.x;         // batch 0..127
    const int dirs = blockIdx.y;         // 0 fwd, 1 bwd (kernel-scalar)
    const int tid  = threadIdx.x;
    const int w    = tid >> 6;           // hid group: cols 16w..16w+15
    const int lane = tid & 63;
    const int r    = lane & 15;          // frag col -> hid sub-index
    const int q    = lane >> 4;          // frag k-group
    const int hid  = 16 * w + r;
    const int hid4 = hid * 4;            // element offset of lane's uint2

    __shared__ ScanSM sm;

    // ---- persistent B-fragments: Whh (f32) -> bf16 with exp2-domain scale --
    const float* __restrict__ Wd = dirs ? Whh_b : Whh_f;
    bfv8 bfr[4][4];                      // [gate][ktile]
    #pragma unroll
    for (int g = 0; g < 4; ++g) {
        const float wscale = (g == 2) ? GSCALE : NSCALE;
        #pragma unroll
        for (int kk = 0; kk < 4; ++kk) {
            const float* src = Wd + (size_t)(g * 128 + hid) * 128 + kk * 32 + q * 8;
            float4 lo = *(const float4*)(src);
            float4 hi = *(const float4*)(src + 4);
            bfv8 v;
            v[0] = (short)f2bf(lo.x * wscale); v[1] = (short)f2bf(lo.y * wscale);
            v[2] = (short)f2bf(lo.z * wscale); v[3] = (short)f2bf(lo.w * wscale);
            v[4] = (short)f2bf(hi.x * wscale); v[5] = (short)f2bf(hi.y * wscale);
            v[6] = (short)f2bf(hi.z * wscale); v[7] = (short)f2bf(hi.w * wscale);
            bfr[g][kk] = v;
        }
    }

    // ---- zero h buf 0 ----
    if (q == 0) sm.h[0][hid] = 0;

    float c0 = 0.f;

    // ---- uniform bases: pre row base (dir half), hs batch base ----
    const unsigned short* pdb = pre + (size_t)b * NG + dirs * 512;
    unsigned short* hsrow = hs + (size_t)b * NL * 256 + dirs * 128;

    int t0 = dirs ? 511 : 0;
    int t1 = dirs ? 510 : 1;
    uint2 pP0 = *(const uint2*)(pdb + (size_t)t0 * (NB * NG) + hid4);
    uint2 pP1 = *(const uint2*)(pdb + (size_t)t1 * (NB * NG) + hid4);
    __syncthreads();

    for (int s = 0; s < 512; s += 2) {
        STEP(s, 0, 1)
        STEP(s + 1, 1, 0)
    }
}

// ---------------------------------------------------------------------------
// 5) LayerNorm: read bf16 hs, write f32 out; one wave per 256-wide row
// ---------------------------------------------------------------------------
__global__ __launch_bounds__(256) void ln_kernel(const unsigned short* __restrict__ hs,
                                                 float* __restrict__ out,
                                                 const float* __restrict__ gamma,
                                                 const float* __restrict__ beta) {
    int row = blockIdx.x * 4 + (threadIdx.x >> 6);
    int lane = threadIdx.x & 63;
    const ushort4 hv = ((const ushort4*)(hs + (size_t)row * 256))[lane];
    float a = bf2f(hv.x), bb = bf2f(hv.y), c = bf2f(hv.z), d = bf2f(hv.w);
    float s = (a + bb) + (c + d);
    float s2 = (a * a + bb * bb) + (c * c + d * d);
    #pragma unroll
    for (int o = 32; o > 0; o >>= 1) {
        s += __shfl_xor(s, o);
        s2 += __shfl_xor(s2, o);
    }
    float mu = s * (1.f / 256.f);
    float var = s2 * (1.f / 256.f) - mu * mu;
    float rs = rsqrtf(var + 1e-5f);
    float4 gv = ((const float4*)gamma)[lane];
    float4 bv = ((const float4*)beta)[lane];
    float4 rr;
    rr.x = (a - mu) * rs * gv.x + bv.x;
    rr.y = (bb - mu) * rs * gv.y + bv.y;
    rr.z = (c - mu) * rs * gv.z + bv.z;
    rr.w = (d - mu) * rs * gv.w + bv.w;
    ((float4*)(out + (size_t)row * 256))[lane] = rr;
}

// ---------------------------------------------------------------------------
extern "C" void kernel_launch(void* const* d_in, const int* in_sizes, int n_in,
                              void* d_out, int out_size, void* d_ws, size_t ws_size,
                              hipStream_t stream) {
    (void)in_sizes; (void)n_in; (void)out_size; (void)ws_size;
    const float* x     = (const float*)d_in[0];
    const float* Wproj = (const float*)d_in[1];
    const float* bproj = (const float*)d_in[2];
    const float* Wih_f = (const float*)d_in[3];
    const float* Whh_f = (const float*)d_in[4];
    const float* b_f   = (const float*)d_in[5];
    const float* Wih_b = (const float*)d_in[6];
    const float* Whh_b = (const float*)d_in[7];
    const float* b_b   = (const float*)d_in[8];
    const float* gamma = (const float*)d_in[9];
    const float* beta  = (const float*)d_in[10];
    float* out = (float*)d_out;

    // workspace layout (hs reuses xbt's region: xbt dead after gemm_pre)
    char* ws = (char*)d_ws;
    unsigned short* pre  = (unsigned short*)ws;                   // 65536*1024*2 = 134217728
    unsigned short* xbt  = (unsigned short*)(ws + 134217728);     // 65536*256*2  =  33554432
    unsigned short* hs   = xbt;                                   // alias, 65536*256*2
    unsigned short* weff = (unsigned short*)(ws + 167772160);     // 1024*256*2   =    524288
    float*          beff = (float*)(ws + 168296448);              // 1024*4

    convert_kernel<<<16384, 256, 0, stream>>>(x, xbt);
    fold_kernel<<<1024, 256, 0, stream>>>(Wproj, bproj, Wih_f, b_f, Wih_b, b_b, weff, beff);
    gemm_pre<<<dim3(8, 512), 256, 0, stream>>>(xbt, weff, beff, pre);
    scan_kernel<<<dim3(128, 2), 512, 0, stream>>>(pre, Whh_f, Whh_b, hs);
    ln_kernel<<<16384, 256, 0, stream>>>(hs, out, gamma, beta);
}